// Round 4
// baseline (317.860 us; speedup 1.0000x reference)
//
#include <hip/hip_runtime.h>

// GATConv fused pipeline, MI355X.
// R3: replaced {global hist + 3-kernel scan + random scatter + aggr} with a
// 2-level counting sort (LDS-staged, coalesced writes) + fused fine kernel.
// Packing invariant: src < 2^17 (n <= 131072), dst_low = 8 bits.

#define NEG_SLOPE 0.2f
#define NBC_MAX 512      // max coarse buckets (supports n <= 131072)
#define SCAP 6144        // fine-kernel LDS staging capacity (edges/bucket)

__device__ __forceinline__ float leaky(float v) {
    return v > 0.f ? v : NEG_SLOPE * v;
}
__device__ __forceinline__ float wave_sum(float v) {
    for (int o = 32; o; o >>= 1) v += __shfl_xor(v, o);
    return v;
}
__device__ __forceinline__ float wave_max(float v) {
    for (int o = 32; o; o >>= 1) v = fmaxf(v, __shfl_xor(v, o));
    return v;
}

// exclusive scan of sd[0..len) in place; sd must have len+1 slots.
// wave 0 does the work; all threads must call (has barriers).
__device__ __forceinline__ void lds_excl_scan(int* sd, int len) {
    __syncthreads();
    if (threadIdx.x < 64) {
        int lane = threadIdx.x;
        int carry = 0;
        for (int c0 = 0; c0 < len; c0 += 64) {
            int idx = c0 + lane;
            int v = (idx < len) ? sd[idx] : 0;
            int s = v;
            for (int off = 1; off < 64; off <<= 1) {
                int t = __shfl_up(s, off);
                if (lane >= off) s += t;
            }
            if (idx < len) sd[idx] = carry + s - v;
            carry += __shfl(s, 63);
        }
        if (lane == 0) sd[len] = carry;
    }
    __syncthreads();
}

// ------------------------------------------------- h = x@W, a_src, a_dst
__global__ __launch_bounds__(256) void k_gemm(
    const float* __restrict__ x, const float* __restrict__ Wg,
    const float* __restrict__ att_s, const float* __restrict__ att_d,
    float* __restrict__ h, float* __restrict__ a_src, float* __restrict__ a_dst,
    int n) {
    __shared__ float Wl[128 * 64];  // 32 KB
    {
        const float4* s4 = (const float4*)Wg;
        float4* d4 = (float4*)Wl;
        for (int i = threadIdx.x; i < 128 * 64 / 4; i += 256) d4[i] = s4[i];
    }
    __syncthreads();
    const int lane = threadIdx.x & 63;
    const float as_l = att_s[lane];
    const float ad_l = att_d[lane];
    int gw = (blockIdx.x << 2) + (threadIdx.x >> 6);
    int r0 = __builtin_amdgcn_readfirstlane(gw << 2);
    if (r0 >= n) return;
    if (r0 + 4 <= n) {
        const float* __restrict__ xr = x + (size_t)r0 * 128;
        float acc0 = 0.f, acc1 = 0.f, acc2 = 0.f, acc3 = 0.f;
        for (int k = 0; k < 128; k += 4) {
            float w0 = Wl[(k + 0) * 64 + lane];
            float w1 = Wl[(k + 1) * 64 + lane];
            float w2 = Wl[(k + 2) * 64 + lane];
            float w3 = Wl[(k + 3) * 64 + lane];
            float4 x0 = *(const float4*)(xr + k);
            float4 x1 = *(const float4*)(xr + 128 + k);
            float4 x2 = *(const float4*)(xr + 256 + k);
            float4 x3 = *(const float4*)(xr + 384 + k);
            acc0 += x0.x * w0 + x0.y * w1 + x0.z * w2 + x0.w * w3;
            acc1 += x1.x * w0 + x1.y * w1 + x1.z * w2 + x1.w * w3;
            acc2 += x2.x * w0 + x2.y * w1 + x2.z * w2 + x2.w * w3;
            acc3 += x3.x * w0 + x3.y * w1 + x3.z * w2 + x3.w * w3;
        }
        float* hp = h + (size_t)r0 * 64 + lane;
        hp[0] = acc0; hp[64] = acc1; hp[128] = acc2; hp[192] = acc3;
        float s;
        s = wave_sum(acc0 * as_l); if (!lane) a_src[r0 + 0] = s;
        s = wave_sum(acc0 * ad_l); if (!lane) a_dst[r0 + 0] = s;
        s = wave_sum(acc1 * as_l); if (!lane) a_src[r0 + 1] = s;
        s = wave_sum(acc1 * ad_l); if (!lane) a_dst[r0 + 1] = s;
        s = wave_sum(acc2 * as_l); if (!lane) a_src[r0 + 2] = s;
        s = wave_sum(acc2 * ad_l); if (!lane) a_dst[r0 + 2] = s;
        s = wave_sum(acc3 * as_l); if (!lane) a_src[r0 + 3] = s;
        s = wave_sum(acc3 * ad_l); if (!lane) a_dst[r0 + 3] = s;
    } else {
        for (int rr = 0; rr < 4 && r0 + rr < n; ++rr) {
            const float* xp = x + (size_t)(r0 + rr) * 128;
            float acc = 0.f;
            for (int k = 0; k < 128; ++k) acc += xp[k] * Wl[k * 64 + lane];
            h[(size_t)(r0 + rr) * 64 + lane] = acc;
            float s = wave_sum(acc * as_l); if (!lane) a_src[r0 + rr] = s;
            float t = wave_sum(acc * ad_l); if (!lane) a_dst[r0 + rr] = t;
        }
    }
}

// ------------------------------------------------- coarse histogram
__global__ __launch_bounds__(256) void k_chist(const int* __restrict__ dstv,
                                               int* __restrict__ chist,
                                               int e, int nbc) {
    __shared__ int hl[NBC_MAX];
    for (int t = threadIdx.x; t < nbc; t += 256) hl[t] = 0;
    __syncthreads();
    const int base = blockIdx.x * 4096;
    for (int k = 0; k < 16; ++k) {
        int i = base + k * 256 + threadIdx.x;
        if (i < e) atomicAdd(&hl[dstv[i] >> 8], 1);
    }
    __syncthreads();
    for (int t = threadIdx.x; t < nbc; t += 256) {
        int c = hl[t];
        if (c) atomicAdd(&chist[t], c);
    }
}

// ------------------------------------------------- coarse scan (1 block)
__global__ __launch_bounds__(256) void k_cscan(const int* __restrict__ chist,
                                               int* __restrict__ cbase,
                                               int* __restrict__ gcursor, int nbc) {
    __shared__ int sc[NBC_MAX + 1];
    for (int t = threadIdx.x; t < nbc; t += 256) sc[t] = chist[t];
    lds_excl_scan(sc, nbc);
    for (int t = threadIdx.x; t <= nbc; t += 256) {
        cbase[t] = sc[t];
        if (t < nbc) gcursor[t] = sc[t];
    }
}

// ------------------------------------------------- coarse scatter (LDS reorder)
// block handles 4096 edges; writes packed words grouped by bucket (coalesced runs)
__global__ __launch_bounds__(256) void k_cscatter(
    const int* __restrict__ srcv, const int* __restrict__ dstv,
    int* __restrict__ gcursor, int* __restrict__ words, int e, int nbc) {
    __shared__ int sc[NBC_MAX + 1];
    __shared__ int offs[NBC_MAX];
    __shared__ int gbase[NBC_MAX];
    __shared__ int2 staged[4096];
    for (int t = threadIdx.x; t < nbc; t += 256) { sc[t] = 0; offs[t] = 0; }
    __syncthreads();
    const int base = blockIdx.x * 4096;
    int s_[16], d_[16];
#pragma unroll
    for (int k = 0; k < 16; ++k) {
        int i = base + k * 256 + threadIdx.x;
        if (i < e) {
            s_[k] = srcv[i];
            d_[k] = dstv[i];
            atomicAdd(&sc[d_[k] >> 8], 1);
        } else {
            d_[k] = -1;
        }
    }
    lds_excl_scan(sc, nbc);  // barriers inside
    for (int t = threadIdx.x; t < nbc; t += 256) {
        int c = sc[t + 1] - sc[t];
        if (c) gbase[t] = atomicAdd(&gcursor[t], c);
    }
    __syncthreads();
#pragma unroll
    for (int k = 0; k < 16; ++k) {
        if (d_[k] >= 0) {
            int b = d_[k] >> 8;
            int r = atomicAdd(&offs[b], 1);
            staged[sc[b] + r] = make_int2(s_[k], d_[k]);
        }
    }
    __syncthreads();
    const int tot = sc[nbc];
    for (int p = threadIdx.x; p < tot; p += 256) {
        int2 pr = staged[p];
        int b = pr.y >> 8;
        int word = ((pr.y & 255) << 17) | pr.x;  // dst_low:8 | src:17
        words[gbase[b] + (p - sc[b])] = word;
    }
}

// ------------------------------------------------- fine: local CSR + softmax + aggregate
// one block per coarse bucket: 256 dst nodes, ~4.3K edges, all staging in LDS
__global__ __launch_bounds__(256) void k_fine(
    const int* __restrict__ words, const int* __restrict__ cbase,
    const float* __restrict__ h, const float* __restrict__ a_src,
    const float* __restrict__ a_dst, float* __restrict__ out, int n) {
    __shared__ int rp[257];
    __shared__ int offs[256];
    __shared__ int2 sorted[SCAP];  // (src, bits(a_src[src]))
    const int b = blockIdx.x;
    const int d0 = b << 8;
    const int ndl = min(256, n - d0);
    const int base = cbase[b];
    const int cnt = cbase[b + 1] - base;
    const int tid = threadIdx.x;
    rp[tid] = 0;
    offs[tid] = 0;
    if (tid == 0) rp[256] = 0;
    __syncthreads();
    const bool staged_ok = (cnt <= SCAP);
    if (staged_ok) {
        for (int p = tid; p < cnt; p += 256) {
            int w = words[base + p];
            atomicAdd(&rp[(w >> 17) & 255], 1);
        }
        lds_excl_scan(rp, 256);
        for (int p = tid; p < cnt; p += 256) {
            int w = words[base + p];
            int dl = (w >> 17) & 255;
            int src = w & 0x1FFFF;
            int r = atomicAdd(&offs[dl], 1);
            sorted[rp[dl] + r] = make_int2(src, __float_as_int(a_src[src]));
        }
        __syncthreads();
    }
    const int wid = tid >> 6;
    const int lane = tid & 63;
    const int r = lane >> 4;          // row group
    const int f0 = (lane & 15) << 2;  // feature quad

    for (int dl = wid; dl < ndl; dl += 4) {
        const int d = d0 + dl;
        const float adst = a_dst[d];
        const float e_self = leaky(a_src[d] + adst);
        float lm = -1e30f, ls = 0.f;
        float m, inv;
        if (staged_ok) {
            const int segb = rp[dl];
            const int deg = rp[dl + 1] - segb;
            for (int j = lane; j < deg; j += 64) {
                float ev = leaky(__int_as_float(sorted[segb + j].y) + adst);
                if (ev > lm) { ls = ls * __expf(lm - ev) + 1.f; lm = ev; }
                else ls += __expf(ev - lm);
            }
            m = fmaxf(wave_max(lm), e_self);
            ls *= __expf(lm - m);
            const float denom = wave_sum(ls) + __expf(e_self - m);
            inv = 1.0f / (denom + 1e-16f);
            float4 acc = {0.f, 0.f, 0.f, 0.f};
            if (r == 0) {
                float wgt = __expf(e_self - m) * inv;
                const float4 hv = *(const float4*)(h + (size_t)d * 64 + f0);
                acc.x = wgt * hv.x; acc.y = wgt * hv.y;
                acc.z = wgt * hv.z; acc.w = wgt * hv.w;
            }
            for (int c0 = 0; c0 < deg; c0 += 4) {
                int j = c0 + r;
                if (j < deg) {
                    int2 pr = sorted[segb + j];
                    float wgt = __expf(leaky(__int_as_float(pr.y) + adst) - m) * inv;
                    const float4 hv = *(const float4*)(h + (size_t)pr.x * 64 + f0);
                    acc.x += wgt * hv.x; acc.y += wgt * hv.y;
                    acc.z += wgt * hv.z; acc.w += wgt * hv.w;
                }
            }
            acc.x += __shfl_xor(acc.x, 16); acc.y += __shfl_xor(acc.y, 16);
            acc.z += __shfl_xor(acc.z, 16); acc.w += __shfl_xor(acc.w, 16);
            acc.x += __shfl_xor(acc.x, 32); acc.y += __shfl_xor(acc.y, 32);
            acc.z += __shfl_xor(acc.z, 32); acc.w += __shfl_xor(acc.w, 32);
            if (lane < 16) *(float4*)(out + (size_t)d * 64 + f0) = acc;
        } else {
            // fallback (bucket overflowed LDS): stream from global, correct but slow
            for (int j = lane; j < cnt; j += 64) {
                int w = words[base + j];
                if (((w >> 17) & 255) == dl) {
                    float ev = leaky(a_src[w & 0x1FFFF] + adst);
                    if (ev > lm) { ls = ls * __expf(lm - ev) + 1.f; lm = ev; }
                    else ls += __expf(ev - lm);
                }
            }
            m = fmaxf(wave_max(lm), e_self);
            ls *= __expf(lm - m);
            const float denom = wave_sum(ls) + __expf(e_self - m);
            inv = 1.0f / (denom + 1e-16f);
            float4 acc = {0.f, 0.f, 0.f, 0.f};
            if (r == 0) {
                float wgt = __expf(e_self - m) * inv;
                const float4 hv = *(const float4*)(h + (size_t)d * 64 + f0);
                acc.x = wgt * hv.x; acc.y = wgt * hv.y;
                acc.z = wgt * hv.z; acc.w = wgt * hv.w;
            }
            for (int c0 = 0; c0 < cnt; c0 += 4) {
                int j = c0 + r;
                if (j < cnt) {
                    int w = words[base + j];
                    if (((w >> 17) & 255) == dl) {
                        int src = w & 0x1FFFF;
                        float wgt = __expf(leaky(a_src[src] + adst) - m) * inv;
                        const float4 hv = *(const float4*)(h + (size_t)src * 64 + f0);
                        acc.x += wgt * hv.x; acc.y += wgt * hv.y;
                        acc.z += wgt * hv.z; acc.w += wgt * hv.w;
                    }
                }
            }
            acc.x += __shfl_xor(acc.x, 16); acc.y += __shfl_xor(acc.y, 16);
            acc.z += __shfl_xor(acc.z, 16); acc.w += __shfl_xor(acc.w, 16);
            acc.x += __shfl_xor(acc.x, 32); acc.y += __shfl_xor(acc.y, 32);
            acc.z += __shfl_xor(acc.z, 32); acc.w += __shfl_xor(acc.w, 32);
            if (lane < 16) *(float4*)(out + (size_t)d * 64 + f0) = acc;
        }
    }
}

extern "C" void kernel_launch(void* const* d_in, const int* in_sizes, int n_in,
                              void* d_out, int out_size, void* d_ws, size_t ws_size,
                              hipStream_t stream) {
    const float* x = (const float*)d_in[0];
    const float* W = (const float*)d_in[1];
    const float* att_s = (const float*)d_in[2];
    const float* att_d = (const float*)d_in[3];
    const int* ei = (const int*)d_in[4];
    const int n = in_sizes[0] / 128;
    const int e = in_sizes[4] / 2;
    const int* srcv = ei;
    const int* dstv = ei + e;
    float* out = (float*)d_out;

    char* ws = (char*)d_ws;
    size_t off = 0;
    auto carve = [&](size_t bytes) -> void* {
        void* p = ws + off;
        off = (off + bytes + 63) & ~(size_t)63;
        return p;
    };
    float* h      = (float*)carve((size_t)n * 64 * 4);
    float* a_src  = (float*)carve((size_t)n * 4);
    float* a_dst  = (float*)carve((size_t)n * 4);
    int* chist    = (int*)carve((size_t)(NBC_MAX + 1) * 4);  // chist+gcursor
    int* gcursor  = (int*)carve((size_t)NBC_MAX * 4);        //  contiguous-ish
    int* cbase    = (int*)carve((size_t)(NBC_MAX + 1) * 4);
    int* words    = (int*)carve((size_t)e * 4);
    (void)ws_size; (void)n_in; (void)out_size;

    const int nbc = (n + 255) >> 8;          // coarse buckets (<= 512)
    const int neb = (e + 4095) / 4096;       // edge-chunk blocks

    // zero chist + gcursor (contiguous carves)
    size_t zspan = (size_t)((char*)(gcursor + NBC_MAX) - (char*)chist);
    hipMemsetAsync(chist, 0, zspan, stream);

    k_gemm<<<(n + 15) / 16, 256, 0, stream>>>(x, W, att_s, att_d, h, a_src, a_dst, n);
    k_chist<<<neb, 256, 0, stream>>>(dstv, chist, e, nbc);
    k_cscan<<<1, 256, 0, stream>>>(chist, cbase, gcursor, nbc);
    k_cscatter<<<neb, 256, 0, stream>>>(srcv, dstv, gcursor, words, e, nbc);
    k_fine<<<nbc, 256, 0, stream>>>(words, cbase, h, a_src, a_dst, out, n);
}

// Round 5
// 195.390 us; speedup vs baseline: 1.6268x; 1.6268x over previous
//
#include <hip/hip_runtime.h>

// GATConv fused pipeline, MI355X.
// R5: 2-level counting sort kept; fine-sort split OUT of aggregation
// (R4's fusion collapsed parallelism: 391 blocks, 16% occupancy).
// k_aggr back to wave-per-dst grid (25K blocks); h stored bf16 to halve
// the random-gather traffic. Packing: word = dst_low:8 | src:17 (n<=131072).

#define NEG_SLOPE 0.2f
#define NBC_MAX 512
#define SCAP 6144

__device__ __forceinline__ float leaky(float v) {
    return v > 0.f ? v : NEG_SLOPE * v;
}
__device__ __forceinline__ float wave_sum(float v) {
    for (int o = 32; o; o >>= 1) v += __shfl_xor(v, o);
    return v;
}
__device__ __forceinline__ float wave_max(float v) {
    for (int o = 32; o; o >>= 1) v = fmaxf(v, __shfl_xor(v, o));
    return v;
}
__device__ __forceinline__ unsigned short f2bf(float f) {
    unsigned b = __float_as_uint(f);
    return (unsigned short)((b + 0x7FFFu + ((b >> 16) & 1u)) >> 16);
}
__device__ __forceinline__ float bf2f(unsigned short u) {
    return __uint_as_float(((unsigned)u) << 16);
}

// exclusive scan of sd[0..len) in place; sd must have len+1 slots.
__device__ __forceinline__ void lds_excl_scan(int* sd, int len) {
    __syncthreads();
    if (threadIdx.x < 64) {
        int lane = threadIdx.x;
        int carry = 0;
        for (int c0 = 0; c0 < len; c0 += 64) {
            int idx = c0 + lane;
            int v = (idx < len) ? sd[idx] : 0;
            int s = v;
            for (int off = 1; off < 64; off <<= 1) {
                int t = __shfl_up(s, off);
                if (lane >= off) s += t;
            }
            if (idx < len) sd[idx] = carry + s - v;
            carry += __shfl(s, 63);
        }
        if (lane == 0) sd[len] = carry;
    }
    __syncthreads();
}

// ------------------------------------------------- h(bf16) = x@W, a_src, a_dst
__global__ __launch_bounds__(256) void k_gemm(
    const float* __restrict__ x, const float* __restrict__ Wg,
    const float* __restrict__ att_s, const float* __restrict__ att_d,
    unsigned short* __restrict__ h2, float* __restrict__ a_src,
    float* __restrict__ a_dst, int n) {
    __shared__ float Wl[128 * 64];  // 32 KB
    {
        const float4* s4 = (const float4*)Wg;
        float4* d4 = (float4*)Wl;
        for (int i = threadIdx.x; i < 128 * 64 / 4; i += 256) d4[i] = s4[i];
    }
    __syncthreads();
    const int lane = threadIdx.x & 63;
    const float as_l = att_s[lane];
    const float ad_l = att_d[lane];
    int gw = (blockIdx.x << 2) + (threadIdx.x >> 6);
    int r0 = __builtin_amdgcn_readfirstlane(gw << 2);
    if (r0 >= n) return;
    if (r0 + 4 <= n) {
        const float* __restrict__ xr = x + (size_t)r0 * 128;
        float acc0 = 0.f, acc1 = 0.f, acc2 = 0.f, acc3 = 0.f;
        for (int k = 0; k < 128; k += 4) {
            float w0 = Wl[(k + 0) * 64 + lane];
            float w1 = Wl[(k + 1) * 64 + lane];
            float w2 = Wl[(k + 2) * 64 + lane];
            float w3 = Wl[(k + 3) * 64 + lane];
            float4 x0 = *(const float4*)(xr + k);
            float4 x1 = *(const float4*)(xr + 128 + k);
            float4 x2 = *(const float4*)(xr + 256 + k);
            float4 x3 = *(const float4*)(xr + 384 + k);
            acc0 += x0.x * w0 + x0.y * w1 + x0.z * w2 + x0.w * w3;
            acc1 += x1.x * w0 + x1.y * w1 + x1.z * w2 + x1.w * w3;
            acc2 += x2.x * w0 + x2.y * w1 + x2.z * w2 + x2.w * w3;
            acc3 += x3.x * w0 + x3.y * w1 + x3.z * w2 + x3.w * w3;
        }
        unsigned short* hp = h2 + (size_t)r0 * 64 + lane;
        hp[0] = f2bf(acc0); hp[64] = f2bf(acc1);
        hp[128] = f2bf(acc2); hp[192] = f2bf(acc3);
        float s;
        s = wave_sum(acc0 * as_l); if (!lane) a_src[r0 + 0] = s;
        s = wave_sum(acc0 * ad_l); if (!lane) a_dst[r0 + 0] = s;
        s = wave_sum(acc1 * as_l); if (!lane) a_src[r0 + 1] = s;
        s = wave_sum(acc1 * ad_l); if (!lane) a_dst[r0 + 1] = s;
        s = wave_sum(acc2 * as_l); if (!lane) a_src[r0 + 2] = s;
        s = wave_sum(acc2 * ad_l); if (!lane) a_dst[r0 + 2] = s;
        s = wave_sum(acc3 * as_l); if (!lane) a_src[r0 + 3] = s;
        s = wave_sum(acc3 * ad_l); if (!lane) a_dst[r0 + 3] = s;
    } else {
        for (int rr = 0; rr < 4 && r0 + rr < n; ++rr) {
            const float* xp = x + (size_t)(r0 + rr) * 128;
            float acc = 0.f;
            for (int k = 0; k < 128; ++k) acc += xp[k] * Wl[k * 64 + lane];
            h2[(size_t)(r0 + rr) * 64 + lane] = f2bf(acc);
            float s = wave_sum(acc * as_l); if (!lane) a_src[r0 + rr] = s;
            float t = wave_sum(acc * ad_l); if (!lane) a_dst[r0 + rr] = t;
        }
    }
}

// ------------------------------------------------- coarse histogram
__global__ __launch_bounds__(256) void k_chist(const int* __restrict__ dstv,
                                               int* __restrict__ chist,
                                               int e, int nbc) {
    __shared__ int hl[NBC_MAX];
    for (int t = threadIdx.x; t < nbc; t += 256) hl[t] = 0;
    __syncthreads();
    const int base = blockIdx.x * 4096;
    for (int k = 0; k < 16; ++k) {
        int i = base + k * 256 + threadIdx.x;
        if (i < e) atomicAdd(&hl[dstv[i] >> 8], 1);
    }
    __syncthreads();
    for (int t = threadIdx.x; t < nbc; t += 256) {
        int c = hl[t];
        if (c) atomicAdd(&chist[t], c);
    }
}

// ------------------------------------------------- coarse scan (1 block)
__global__ __launch_bounds__(256) void k_cscan(const int* __restrict__ chist,
                                               int* __restrict__ cbase,
                                               int* __restrict__ gcursor, int nbc) {
    __shared__ int sc[NBC_MAX + 1];
    for (int t = threadIdx.x; t < nbc; t += 256) sc[t] = chist[t];
    lds_excl_scan(sc, nbc);
    for (int t = threadIdx.x; t <= nbc; t += 256) {
        cbase[t] = sc[t];
        if (t < nbc) gcursor[t] = sc[t];
    }
}

// ------------------------------------------------- coarse scatter (LDS reorder)
__global__ __launch_bounds__(256) void k_cscatter(
    const int* __restrict__ srcv, const int* __restrict__ dstv,
    int* __restrict__ gcursor, int* __restrict__ words, int e, int nbc) {
    __shared__ int sc[NBC_MAX + 1];
    __shared__ int offs[NBC_MAX];
    __shared__ int gbase[NBC_MAX];
    __shared__ int2 staged[4096];
    for (int t = threadIdx.x; t < nbc; t += 256) { sc[t] = 0; offs[t] = 0; }
    __syncthreads();
    const int base = blockIdx.x * 4096;
    int s_[16], d_[16];
#pragma unroll
    for (int k = 0; k < 16; ++k) {
        int i = base + k * 256 + threadIdx.x;
        if (i < e) {
            s_[k] = srcv[i];
            d_[k] = dstv[i];
            atomicAdd(&sc[d_[k] >> 8], 1);
        } else {
            d_[k] = -1;
        }
    }
    lds_excl_scan(sc, nbc);
    for (int t = threadIdx.x; t < nbc; t += 256) {
        int c = sc[t + 1] - sc[t];
        if (c) gbase[t] = atomicAdd(&gcursor[t], c);
    }
    __syncthreads();
#pragma unroll
    for (int k = 0; k < 16; ++k) {
        if (d_[k] >= 0) {
            int b = d_[k] >> 8;
            int r = atomicAdd(&offs[b], 1);
            staged[sc[b] + r] = make_int2(s_[k], d_[k]);
        }
    }
    __syncthreads();
    const int tot = sc[nbc];
    for (int p = threadIdx.x; p < tot; p += 256) {
        int2 pr = staged[p];
        int b = pr.y >> 8;
        int word = ((pr.y & 255) << 17) | pr.x;  // dst_low:8 | src:17
        words[gbase[b] + (p - sc[b])] = word;
    }
}

// ------------------------------------------------- fine sort: words -> words2 + rowptr
// one block per coarse bucket; LDS counting sort over 256 dst_low keys
__global__ __launch_bounds__(256) void k_fsort(
    const int* __restrict__ words, int* __restrict__ words2,
    const int* __restrict__ cbase, int* __restrict__ rowptr,
    int n, int e) {
    __shared__ int rp[257];
    __shared__ int offs[256];
    __shared__ int staged[SCAP];
    __shared__ int sorted_[SCAP];
    const int b = blockIdx.x;
    const int base = cbase[b];
    const int cnt = cbase[b + 1] - base;
    const int tid = threadIdx.x;
    rp[tid] = 0;
    offs[tid] = 0;
    if (tid == 0) rp[256] = 0;
    __syncthreads();
    if (cnt <= SCAP) {
        for (int p = tid; p < cnt; p += 256) {
            int w = words[base + p];
            staged[p] = w;
            atomicAdd(&rp[(w >> 17) & 255], 1);
        }
        lds_excl_scan(rp, 256);
        for (int p = tid; p < cnt; p += 256) {
            int w = staged[p];
            int dl = (w >> 17) & 255;
            int r = atomicAdd(&offs[dl], 1);
            sorted_[rp[dl] + r] = w;
        }
        __syncthreads();
        for (int p = tid; p < cnt; p += 256) words2[base + p] = sorted_[p];
    } else {
        // overflow fallback: 2-pass, scattered global writes (rare)
        for (int p = tid; p < cnt; p += 256)
            atomicAdd(&rp[(words[base + p] >> 17) & 255], 1);
        lds_excl_scan(rp, 256);
        for (int p = tid; p < cnt; p += 256) {
            int w = words[base + p];
            int dl = (w >> 17) & 255;
            int r = atomicAdd(&offs[dl], 1);
            words2[base + rp[dl] + r] = w;
        }
    }
    const int d0 = b << 8;
    const int ndl = min(256, n - d0);
    if (tid < ndl) rowptr[d0 + tid] = base + rp[tid];
    if (b == (int)gridDim.x - 1 && tid == 0) rowptr[n] = e;
}

// ------------------------------------------------- softmax + aggregate
// wave per dst; phase 3: 4 rows/iter, bf16 h gather (ushort4 = 8B/lane)
__global__ __launch_bounds__(256) void k_aggr(
    const unsigned short* __restrict__ h2, const float* __restrict__ a_src,
    const float* __restrict__ a_dst, const int* __restrict__ rowptr,
    const int* __restrict__ words2, float* __restrict__ out, int n) {
    const int lane = threadIdx.x & 63;
    int d = (blockIdx.x << 2) + (threadIdx.x >> 6);
    if (d >= n) return;
    d = __builtin_amdgcn_readfirstlane(d);
    const int base = rowptr[d];
    const int deg = rowptr[d + 1] - base;
    const float adst = a_dst[d];
    const float e_self = leaky(a_src[d] + adst);

    float lm = -1e30f, ls = 0.f;
    for (int j = lane; j < deg; j += 64) {
        int src = words2[base + j] & 0x1FFFF;
        float ev = leaky(a_src[src] + adst);
        if (ev > lm) { ls = ls * __expf(lm - ev) + 1.f; lm = ev; }
        else ls += __expf(ev - lm);
    }
    const float m = fmaxf(wave_max(lm), e_self);
    ls *= __expf(lm - m);
    const float denom = wave_sum(ls) + __expf(e_self - m);
    const float inv = 1.0f / (denom + 1e-16f);

    const int r = lane >> 4;          // row group
    const int f0 = (lane & 15) << 2;  // feature quad
    float4 acc = {0.f, 0.f, 0.f, 0.f};
    if (r == 0) {
        float wgt = __expf(e_self - m) * inv;
        ushort4 u = *(const ushort4*)(h2 + (size_t)d * 64 + f0);
        acc.x = wgt * bf2f(u.x); acc.y = wgt * bf2f(u.y);
        acc.z = wgt * bf2f(u.z); acc.w = wgt * bf2f(u.w);
    }
    for (int c0 = 0; c0 < deg; c0 += 4) {
        int j = c0 + r;
        if (j < deg) {
            int src = words2[base + j] & 0x1FFFF;
            float wgt = __expf(leaky(a_src[src] + adst) - m) * inv;
            ushort4 u = *(const ushort4*)(h2 + (size_t)src * 64 + f0);
            acc.x += wgt * bf2f(u.x); acc.y += wgt * bf2f(u.y);
            acc.z += wgt * bf2f(u.z); acc.w += wgt * bf2f(u.w);
        }
    }
    acc.x += __shfl_xor(acc.x, 16); acc.y += __shfl_xor(acc.y, 16);
    acc.z += __shfl_xor(acc.z, 16); acc.w += __shfl_xor(acc.w, 16);
    acc.x += __shfl_xor(acc.x, 32); acc.y += __shfl_xor(acc.y, 32);
    acc.z += __shfl_xor(acc.z, 32); acc.w += __shfl_xor(acc.w, 32);
    if (lane < 16) *(float4*)(out + (size_t)d * 64 + f0) = acc;
}

extern "C" void kernel_launch(void* const* d_in, const int* in_sizes, int n_in,
                              void* d_out, int out_size, void* d_ws, size_t ws_size,
                              hipStream_t stream) {
    const float* x = (const float*)d_in[0];
    const float* W = (const float*)d_in[1];
    const float* att_s = (const float*)d_in[2];
    const float* att_d = (const float*)d_in[3];
    const int* ei = (const int*)d_in[4];
    const int n = in_sizes[0] / 128;
    const int e = in_sizes[4] / 2;
    const int* srcv = ei;
    const int* dstv = ei + e;
    float* out = (float*)d_out;

    char* ws = (char*)d_ws;
    size_t off = 0;
    auto carve = [&](size_t bytes) -> void* {
        void* p = ws + off;
        off = (off + bytes + 63) & ~(size_t)63;
        return p;
    };
    unsigned short* h2 = (unsigned short*)carve((size_t)n * 64 * 2);
    float* a_src  = (float*)carve((size_t)n * 4);
    float* a_dst  = (float*)carve((size_t)n * 4);
    int* chist    = (int*)carve((size_t)(NBC_MAX + 1) * 4);  // chist+gcursor zeroed together
    int* gcursor  = (int*)carve((size_t)NBC_MAX * 4);
    int* cbase    = (int*)carve((size_t)(NBC_MAX + 1) * 4);
    int* rowptr   = (int*)carve((size_t)(n + 1) * 4);
    int* words    = (int*)carve((size_t)e * 4);
    int* words2   = (int*)carve((size_t)e * 4);
    (void)ws_size; (void)n_in; (void)out_size;

    const int nbc = (n + 255) >> 8;     // coarse buckets
    const int neb = (e + 4095) / 4096;  // edge-chunk blocks

    size_t zspan = (size_t)((char*)(gcursor + NBC_MAX) - (char*)chist);
    hipMemsetAsync(chist, 0, zspan, stream);

    k_gemm<<<(n + 15) / 16, 256, 0, stream>>>(x, W, att_s, att_d, h2, a_src, a_dst, n);
    k_chist<<<neb, 256, 0, stream>>>(dstv, chist, e, nbc);
    k_cscan<<<1, 256, 0, stream>>>(chist, cbase, gcursor, nbc);
    k_cscatter<<<neb, 256, 0, stream>>>(srcv, dstv, gcursor, words, e, nbc);
    k_fsort<<<nbc, 256, 0, stream>>>(words, words2, cbase, rowptr, n, e);
    k_aggr<<<(n + 3) / 4, 256, 0, stream>>>(h2, a_src, a_dst, rowptr, words2, out, n);
}

// Round 6
// 186.511 us; speedup vs baseline: 1.7042x; 1.0476x over previous
//
#include <hip/hip_runtime.h>

// GATConv fused pipeline, MI355X.
// R6: k_gemm restructured — coalesced global->LDS x staging + broadcast
// ds_read feeds FMAs (R5's per-row broadcast VMEM loads were latency-bound:
// 3.2M chained global_load_dwordx4, VALUBusy 23%).
// Sort pipeline + aggr unchanged from R5 (passed, absmax 0.0156).
// Packing: word = dst_low:8 | src:17 (n<=131072).

#define NEG_SLOPE 0.2f
#define NBC_MAX 512
#define SCAP 6144

__device__ __forceinline__ float leaky(float v) {
    return v > 0.f ? v : NEG_SLOPE * v;
}
__device__ __forceinline__ float wave_sum(float v) {
    for (int o = 32; o; o >>= 1) v += __shfl_xor(v, o);
    return v;
}
__device__ __forceinline__ float wave_max(float v) {
    for (int o = 32; o; o >>= 1) v = fmaxf(v, __shfl_xor(v, o));
    return v;
}
__device__ __forceinline__ unsigned short f2bf(float f) {
    unsigned b = __float_as_uint(f);
    return (unsigned short)((b + 0x7FFFu + ((b >> 16) & 1u)) >> 16);
}
__device__ __forceinline__ float bf2f(unsigned short u) {
    return __uint_as_float(((unsigned)u) << 16);
}

// exclusive scan of sd[0..len) in place; sd must have len+1 slots.
__device__ __forceinline__ void lds_excl_scan(int* sd, int len) {
    __syncthreads();
    if (threadIdx.x < 64) {
        int lane = threadIdx.x;
        int carry = 0;
        for (int c0 = 0; c0 < len; c0 += 64) {
            int idx = c0 + lane;
            int v = (idx < len) ? sd[idx] : 0;
            int s = v;
            for (int off = 1; off < 64; off <<= 1) {
                int t = __shfl_up(s, off);
                if (lane >= off) s += t;
            }
            if (idx < len) sd[idx] = carry + s - v;
            carry += __shfl(s, 63);
        }
        if (lane == 0) sd[len] = carry;
    }
    __syncthreads();
}

// ------------------------------------------------- h(bf16) = x@W, a_src, a_dst
// block: 32 rows; wave: 8 rows x 64 cols (lane = col). x tile staged in LDS.
__global__ __launch_bounds__(256) void k_gemm(
    const float* __restrict__ x, const float* __restrict__ Wg,
    const float* __restrict__ att_s, const float* __restrict__ att_d,
    unsigned short* __restrict__ h2, float* __restrict__ a_src,
    float* __restrict__ a_dst, int n) {
    __shared__ float Wl[128 * 64];   // 32 KB  [k][col]
    __shared__ float Xl[32 * 128];   // 16 KB  [row][k]
    {
        const float4* s4 = (const float4*)Wg;
        float4* d4 = (float4*)Wl;
#pragma unroll
        for (int i = 0; i < 8; ++i) d4[threadIdx.x + i * 256] = s4[threadIdx.x + i * 256];
    }
    const int row0 = blockIdx.x * 32;
    {
        const float4* xg = (const float4*)(x + (size_t)row0 * 128);
        float4* xl4 = (float4*)Xl;
        if (row0 + 32 <= n) {
#pragma unroll
            for (int i = 0; i < 4; ++i)
                xl4[threadIdx.x + i * 256] = xg[threadIdx.x + i * 256];
        } else {
            int nf4 = (n - row0) * 32;
#pragma unroll
            for (int i = 0; i < 4; ++i) {
                int f = threadIdx.x + i * 256;
                xl4[f] = (f < nf4) ? xg[f] : make_float4(0.f, 0.f, 0.f, 0.f);
            }
        }
    }
    const int lane = threadIdx.x & 63;
    const int wave = threadIdx.x >> 6;
    const float as_l = att_s[lane];
    const float ad_l = att_d[lane];
    __syncthreads();

    float acc[8] = {0.f, 0.f, 0.f, 0.f, 0.f, 0.f, 0.f, 0.f};
    const float* xw = Xl + wave * 8 * 128;
    for (int k = 0; k < 128; k += 4) {
        float w0 = Wl[(k + 0) * 64 + lane];
        float w1 = Wl[(k + 1) * 64 + lane];
        float w2 = Wl[(k + 2) * 64 + lane];
        float w3 = Wl[(k + 3) * 64 + lane];
#pragma unroll
        for (int r = 0; r < 8; ++r) {
            float4 xv = *(const float4*)(xw + r * 128 + k);
            acc[r] = fmaf(xv.x, w0,
                     fmaf(xv.y, w1, fmaf(xv.z, w2, fmaf(xv.w, w3, acc[r]))));
        }
    }
    const int r0w = row0 + wave * 8;
#pragma unroll
    for (int r = 0; r < 8; ++r) {
        int row = r0w + r;
        if (row < n) {
            h2[(size_t)row * 64 + lane] = f2bf(acc[r]);
            float s = wave_sum(acc[r] * as_l);
            float t = wave_sum(acc[r] * ad_l);
            if (!lane) { a_src[row] = s; a_dst[row] = t; }
        }
    }
}

// ------------------------------------------------- coarse histogram
__global__ __launch_bounds__(256) void k_chist(const int* __restrict__ dstv,
                                               int* __restrict__ chist,
                                               int e, int nbc) {
    __shared__ int hl[NBC_MAX];
    for (int t = threadIdx.x; t < nbc; t += 256) hl[t] = 0;
    __syncthreads();
    const int base = blockIdx.x * 4096;
    for (int k = 0; k < 16; ++k) {
        int i = base + k * 256 + threadIdx.x;
        if (i < e) atomicAdd(&hl[dstv[i] >> 8], 1);
    }
    __syncthreads();
    for (int t = threadIdx.x; t < nbc; t += 256) {
        int c = hl[t];
        if (c) atomicAdd(&chist[t], c);
    }
}

// ------------------------------------------------- coarse scan (1 block)
__global__ __launch_bounds__(256) void k_cscan(const int* __restrict__ chist,
                                               int* __restrict__ cbase,
                                               int* __restrict__ gcursor, int nbc) {
    __shared__ int sc[NBC_MAX + 1];
    for (int t = threadIdx.x; t < nbc; t += 256) sc[t] = chist[t];
    lds_excl_scan(sc, nbc);
    for (int t = threadIdx.x; t <= nbc; t += 256) {
        cbase[t] = sc[t];
        if (t < nbc) gcursor[t] = sc[t];
    }
}

// ------------------------------------------------- coarse scatter (LDS reorder)
__global__ __launch_bounds__(256) void k_cscatter(
    const int* __restrict__ srcv, const int* __restrict__ dstv,
    int* __restrict__ gcursor, int* __restrict__ words, int e, int nbc) {
    __shared__ int sc[NBC_MAX + 1];
    __shared__ int offs[NBC_MAX];
    __shared__ int gbase[NBC_MAX];
    __shared__ int2 staged[4096];
    for (int t = threadIdx.x; t < nbc; t += 256) { sc[t] = 0; offs[t] = 0; }
    __syncthreads();
    const int base = blockIdx.x * 4096;
    int s_[16], d_[16];
#pragma unroll
    for (int k = 0; k < 16; ++k) {
        int i = base + k * 256 + threadIdx.x;
        if (i < e) {
            s_[k] = srcv[i];
            d_[k] = dstv[i];
            atomicAdd(&sc[d_[k] >> 8], 1);
        } else {
            d_[k] = -1;
        }
    }
    lds_excl_scan(sc, nbc);
    for (int t = threadIdx.x; t < nbc; t += 256) {
        int c = sc[t + 1] - sc[t];
        if (c) gbase[t] = atomicAdd(&gcursor[t], c);
    }
    __syncthreads();
#pragma unroll
    for (int k = 0; k < 16; ++k) {
        if (d_[k] >= 0) {
            int b = d_[k] >> 8;
            int r = atomicAdd(&offs[b], 1);
            staged[sc[b] + r] = make_int2(s_[k], d_[k]);
        }
    }
    __syncthreads();
    const int tot = sc[nbc];
    for (int p = threadIdx.x; p < tot; p += 256) {
        int2 pr = staged[p];
        int b = pr.y >> 8;
        int word = ((pr.y & 255) << 17) | pr.x;  // dst_low:8 | src:17
        words[gbase[b] + (p - sc[b])] = word;
    }
}

// ------------------------------------------------- fine sort: words -> words2 + rowptr
__global__ __launch_bounds__(256) void k_fsort(
    const int* __restrict__ words, int* __restrict__ words2,
    const int* __restrict__ cbase, int* __restrict__ rowptr,
    int n, int e) {
    __shared__ int rp[257];
    __shared__ int offs[256];
    __shared__ int staged[SCAP];
    __shared__ int sorted_[SCAP];
    const int b = blockIdx.x;
    const int base = cbase[b];
    const int cnt = cbase[b + 1] - base;
    const int tid = threadIdx.x;
    rp[tid] = 0;
    offs[tid] = 0;
    if (tid == 0) rp[256] = 0;
    __syncthreads();
    if (cnt <= SCAP) {
        for (int p = tid; p < cnt; p += 256) {
            int w = words[base + p];
            staged[p] = w;
            atomicAdd(&rp[(w >> 17) & 255], 1);
        }
        lds_excl_scan(rp, 256);
        for (int p = tid; p < cnt; p += 256) {
            int w = staged[p];
            int dl = (w >> 17) & 255;
            int r = atomicAdd(&offs[dl], 1);
            sorted_[rp[dl] + r] = w;
        }
        __syncthreads();
        for (int p = tid; p < cnt; p += 256) words2[base + p] = sorted_[p];
    } else {
        for (int p = tid; p < cnt; p += 256)
            atomicAdd(&rp[(words[base + p] >> 17) & 255], 1);
        lds_excl_scan(rp, 256);
        for (int p = tid; p < cnt; p += 256) {
            int w = words[base + p];
            int dl = (w >> 17) & 255;
            int r = atomicAdd(&offs[dl], 1);
            words2[base + rp[dl] + r] = w;
        }
    }
    const int d0 = b << 8;
    const int ndl = min(256, n - d0);
    if (tid < ndl) rowptr[d0 + tid] = base + rp[tid];
    if (b == (int)gridDim.x - 1 && tid == 0) rowptr[n] = e;
}

// ------------------------------------------------- softmax + aggregate
__global__ __launch_bounds__(256) void k_aggr(
    const unsigned short* __restrict__ h2, const float* __restrict__ a_src,
    const float* __restrict__ a_dst, const int* __restrict__ rowptr,
    const int* __restrict__ words2, float* __restrict__ out, int n) {
    const int lane = threadIdx.x & 63;
    int d = (blockIdx.x << 2) + (threadIdx.x >> 6);
    if (d >= n) return;
    d = __builtin_amdgcn_readfirstlane(d);
    const int base = rowptr[d];
    const int deg = rowptr[d + 1] - base;
    const float adst = a_dst[d];
    const float e_self = leaky(a_src[d] + adst);

    float lm = -1e30f, ls = 0.f;
    for (int j = lane; j < deg; j += 64) {
        int src = words2[base + j] & 0x1FFFF;
        float ev = leaky(a_src[src] + adst);
        if (ev > lm) { ls = ls * __expf(lm - ev) + 1.f; lm = ev; }
        else ls += __expf(ev - lm);
    }
    const float m = fmaxf(wave_max(lm), e_self);
    ls *= __expf(lm - m);
    const float denom = wave_sum(ls) + __expf(e_self - m);
    const float inv = 1.0f / (denom + 1e-16f);

    const int r = lane >> 4;          // row group
    const int f0 = (lane & 15) << 2;  // feature quad
    float4 acc = {0.f, 0.f, 0.f, 0.f};
    if (r == 0) {
        float wgt = __expf(e_self - m) * inv;
        ushort4 u = *(const ushort4*)(h2 + (size_t)d * 64 + f0);
        acc.x = wgt * bf2f(u.x); acc.y = wgt * bf2f(u.y);
        acc.z = wgt * bf2f(u.z); acc.w = wgt * bf2f(u.w);
    }
    for (int c0 = 0; c0 < deg; c0 += 4) {
        int j = c0 + r;
        if (j < deg) {
            int src = words2[base + j] & 0x1FFFF;
            float wgt = __expf(leaky(a_src[src] + adst) - m) * inv;
            ushort4 u = *(const ushort4*)(h2 + (size_t)src * 64 + f0);
            acc.x += wgt * bf2f(u.x); acc.y += wgt * bf2f(u.y);
            acc.z += wgt * bf2f(u.z); acc.w += wgt * bf2f(u.w);
        }
    }
    acc.x += __shfl_xor(acc.x, 16); acc.y += __shfl_xor(acc.y, 16);
    acc.z += __shfl_xor(acc.z, 16); acc.w += __shfl_xor(acc.w, 16);
    acc.x += __shfl_xor(acc.x, 32); acc.y += __shfl_xor(acc.y, 32);
    acc.z += __shfl_xor(acc.z, 32); acc.w += __shfl_xor(acc.w, 32);
    if (lane < 16) *(float4*)(out + (size_t)d * 64 + f0) = acc;
}

extern "C" void kernel_launch(void* const* d_in, const int* in_sizes, int n_in,
                              void* d_out, int out_size, void* d_ws, size_t ws_size,
                              hipStream_t stream) {
    const float* x = (const float*)d_in[0];
    const float* W = (const float*)d_in[1];
    const float* att_s = (const float*)d_in[2];
    const float* att_d = (const float*)d_in[3];
    const int* ei = (const int*)d_in[4];
    const int n = in_sizes[0] / 128;
    const int e = in_sizes[4] / 2;
    const int* srcv = ei;
    const int* dstv = ei + e;
    float* out = (float*)d_out;

    char* ws = (char*)d_ws;
    size_t off = 0;
    auto carve = [&](size_t bytes) -> void* {
        void* p = ws + off;
        off = (off + bytes + 63) & ~(size_t)63;
        return p;
    };
    unsigned short* h2 = (unsigned short*)carve((size_t)n * 64 * 2);
    float* a_src  = (float*)carve((size_t)n * 4);
    float* a_dst  = (float*)carve((size_t)n * 4);
    int* chist    = (int*)carve((size_t)(NBC_MAX + 1) * 4);
    int* gcursor  = (int*)carve((size_t)NBC_MAX * 4);
    int* cbase    = (int*)carve((size_t)(NBC_MAX + 1) * 4);
    int* rowptr   = (int*)carve((size_t)(n + 1) * 4);
    int* words    = (int*)carve((size_t)e * 4);
    int* words2   = (int*)carve((size_t)e * 4);
    (void)ws_size; (void)n_in; (void)out_size;

    const int nbc = (n + 255) >> 8;
    const int neb = (e + 4095) / 4096;

    size_t zspan = (size_t)((char*)(gcursor + NBC_MAX) - (char*)chist);
    hipMemsetAsync(chist, 0, zspan, stream);

    k_gemm<<<(n + 31) / 32, 256, 0, stream>>>(x, W, att_s, att_d, h2, a_src, a_dst, n);
    k_chist<<<neb, 256, 0, stream>>>(dstv, chist, e, nbc);
    k_cscan<<<1, 256, 0, stream>>>(chist, cbase, gcursor, nbc);
    k_cscatter<<<neb, 256, 0, stream>>>(srcv, dstv, gcursor, words, e, nbc);
    k_fsort<<<nbc, 256, 0, stream>>>(words, words2, cbase, rowptr, n, e);
    k_aggr<<<(n + 3) / 4, 256, 0, stream>>>(h2, a_src, a_dst, rowptr, words2, out, n);
}

// Round 7
// 168.140 us; speedup vs baseline: 1.8904x; 1.1093x over previous
//
#include <hip/hip_runtime.h>

// GATConv fused pipeline, MI355X.
// R7: k_aggr register-resident edge segments (deg<=64 fast path: one gather+
// one exp per edge, shfl broadcast into 8-row-group x 16B-load aggregation).
// R6 counters: k_aggr 79us, VALUBusy 46% — double exp/gather + narrow loop.
// Sort pipeline + gemm unchanged from R6. word = dst_low:8 | src:17.

#define NEG_SLOPE 0.2f
#define NBC_MAX 512
#define SCAP 6144

__device__ __forceinline__ float leaky(float v) {
    return v > 0.f ? v : NEG_SLOPE * v;
}
__device__ __forceinline__ float wave_sum(float v) {
    for (int o = 32; o; o >>= 1) v += __shfl_xor(v, o);
    return v;
}
__device__ __forceinline__ float wave_max(float v) {
    for (int o = 32; o; o >>= 1) v = fmaxf(v, __shfl_xor(v, o));
    return v;
}
__device__ __forceinline__ unsigned short f2bf(float f) {
    unsigned b = __float_as_uint(f);
    return (unsigned short)((b + 0x7FFFu + ((b >> 16) & 1u)) >> 16);
}
__device__ __forceinline__ float bf2f(unsigned short u) {
    return __uint_as_float(((unsigned)u) << 16);
}
// fma 8 bf16 features (packed in int4) into acc[8] with weight w
__device__ __forceinline__ void bf8_fma(float* acc, int4 u, float w) {
    acc[0] = fmaf(__uint_as_float((unsigned)u.x << 16), w, acc[0]);
    acc[1] = fmaf(__uint_as_float((unsigned)u.x & 0xFFFF0000u), w, acc[1]);
    acc[2] = fmaf(__uint_as_float((unsigned)u.y << 16), w, acc[2]);
    acc[3] = fmaf(__uint_as_float((unsigned)u.y & 0xFFFF0000u), w, acc[3]);
    acc[4] = fmaf(__uint_as_float((unsigned)u.z << 16), w, acc[4]);
    acc[5] = fmaf(__uint_as_float((unsigned)u.z & 0xFFFF0000u), w, acc[5]);
    acc[6] = fmaf(__uint_as_float((unsigned)u.w << 16), w, acc[6]);
    acc[7] = fmaf(__uint_as_float((unsigned)u.w & 0xFFFF0000u), w, acc[7]);
}

// exclusive scan of sd[0..len) in place; sd must have len+1 slots.
__device__ __forceinline__ void lds_excl_scan(int* sd, int len) {
    __syncthreads();
    if (threadIdx.x < 64) {
        int lane = threadIdx.x;
        int carry = 0;
        for (int c0 = 0; c0 < len; c0 += 64) {
            int idx = c0 + lane;
            int v = (idx < len) ? sd[idx] : 0;
            int s = v;
            for (int off = 1; off < 64; off <<= 1) {
                int t = __shfl_up(s, off);
                if (lane >= off) s += t;
            }
            if (idx < len) sd[idx] = carry + s - v;
            carry += __shfl(s, 63);
        }
        if (lane == 0) sd[len] = carry;
    }
    __syncthreads();
}

// ------------------------------------------------- h(bf16) = x@W, a_src, a_dst
__global__ __launch_bounds__(256) void k_gemm(
    const float* __restrict__ x, const float* __restrict__ Wg,
    const float* __restrict__ att_s, const float* __restrict__ att_d,
    unsigned short* __restrict__ h2, float* __restrict__ a_src,
    float* __restrict__ a_dst, int n) {
    __shared__ float Wl[128 * 64];   // 32 KB  [k][col]
    __shared__ float Xl[32 * 128];   // 16 KB  [row][k]
    {
        const float4* s4 = (const float4*)Wg;
        float4* d4 = (float4*)Wl;
#pragma unroll
        for (int i = 0; i < 8; ++i) d4[threadIdx.x + i * 256] = s4[threadIdx.x + i * 256];
    }
    const int row0 = blockIdx.x * 32;
    {
        const float4* xg = (const float4*)(x + (size_t)row0 * 128);
        float4* xl4 = (float4*)Xl;
        if (row0 + 32 <= n) {
#pragma unroll
            for (int i = 0; i < 4; ++i)
                xl4[threadIdx.x + i * 256] = xg[threadIdx.x + i * 256];
        } else {
            int nf4 = (n - row0) * 32;
#pragma unroll
            for (int i = 0; i < 4; ++i) {
                int f = threadIdx.x + i * 256;
                xl4[f] = (f < nf4) ? xg[f] : make_float4(0.f, 0.f, 0.f, 0.f);
            }
        }
    }
    const int lane = threadIdx.x & 63;
    const int wave = threadIdx.x >> 6;
    const float as_l = att_s[lane];
    const float ad_l = att_d[lane];
    __syncthreads();

    float acc[8] = {0.f, 0.f, 0.f, 0.f, 0.f, 0.f, 0.f, 0.f};
    const float* xw = Xl + wave * 8 * 128;
    for (int k = 0; k < 128; k += 4) {
        float w0 = Wl[(k + 0) * 64 + lane];
        float w1 = Wl[(k + 1) * 64 + lane];
        float w2 = Wl[(k + 2) * 64 + lane];
        float w3 = Wl[(k + 3) * 64 + lane];
#pragma unroll
        for (int r = 0; r < 8; ++r) {
            float4 xv = *(const float4*)(xw + r * 128 + k);
            acc[r] = fmaf(xv.x, w0,
                     fmaf(xv.y, w1, fmaf(xv.z, w2, fmaf(xv.w, w3, acc[r]))));
        }
    }
    const int r0w = row0 + wave * 8;
#pragma unroll
    for (int r = 0; r < 8; ++r) {
        int row = r0w + r;
        if (row < n) {
            h2[(size_t)row * 64 + lane] = f2bf(acc[r]);
            float s = wave_sum(acc[r] * as_l);
            float t = wave_sum(acc[r] * ad_l);
            if (!lane) { a_src[row] = s; a_dst[row] = t; }
        }
    }
}

// ------------------------------------------------- coarse histogram
__global__ __launch_bounds__(256) void k_chist(const int* __restrict__ dstv,
                                               int* __restrict__ chist,
                                               int e, int nbc) {
    __shared__ int hl[NBC_MAX];
    for (int t = threadIdx.x; t < nbc; t += 256) hl[t] = 0;
    __syncthreads();
    const int base = blockIdx.x * 4096;
    for (int k = 0; k < 16; ++k) {
        int i = base + k * 256 + threadIdx.x;
        if (i < e) atomicAdd(&hl[dstv[i] >> 8], 1);
    }
    __syncthreads();
    for (int t = threadIdx.x; t < nbc; t += 256) {
        int c = hl[t];
        if (c) atomicAdd(&chist[t], c);
    }
}

// ------------------------------------------------- coarse scan (1 block)
__global__ __launch_bounds__(256) void k_cscan(const int* __restrict__ chist,
                                               int* __restrict__ cbase,
                                               int* __restrict__ gcursor, int nbc) {
    __shared__ int sc[NBC_MAX + 1];
    for (int t = threadIdx.x; t < nbc; t += 256) sc[t] = chist[t];
    lds_excl_scan(sc, nbc);
    for (int t = threadIdx.x; t <= nbc; t += 256) {
        cbase[t] = sc[t];
        if (t < nbc) gcursor[t] = sc[t];
    }
}

// ------------------------------------------------- coarse scatter (LDS reorder)
__global__ __launch_bounds__(256) void k_cscatter(
    const int* __restrict__ srcv, const int* __restrict__ dstv,
    int* __restrict__ gcursor, int* __restrict__ words, int e, int nbc) {
    __shared__ int sc[NBC_MAX + 1];
    __shared__ int offs[NBC_MAX];
    __shared__ int gbase[NBC_MAX];
    __shared__ int2 staged[4096];
    for (int t = threadIdx.x; t < nbc; t += 256) { sc[t] = 0; offs[t] = 0; }
    __syncthreads();
    const int base = blockIdx.x * 4096;
    int s_[16], d_[16];
#pragma unroll
    for (int k = 0; k < 16; ++k) {
        int i = base + k * 256 + threadIdx.x;
        if (i < e) {
            s_[k] = srcv[i];
            d_[k] = dstv[i];
            atomicAdd(&sc[d_[k] >> 8], 1);
        } else {
            d_[k] = -1;
        }
    }
    lds_excl_scan(sc, nbc);
    for (int t = threadIdx.x; t < nbc; t += 256) {
        int c = sc[t + 1] - sc[t];
        if (c) gbase[t] = atomicAdd(&gcursor[t], c);
    }
    __syncthreads();
#pragma unroll
    for (int k = 0; k < 16; ++k) {
        if (d_[k] >= 0) {
            int b = d_[k] >> 8;
            int r = atomicAdd(&offs[b], 1);
            staged[sc[b] + r] = make_int2(s_[k], d_[k]);
        }
    }
    __syncthreads();
    const int tot = sc[nbc];
    for (int p = threadIdx.x; p < tot; p += 256) {
        int2 pr = staged[p];
        int b = pr.y >> 8;
        int word = ((pr.y & 255) << 17) | pr.x;  // dst_low:8 | src:17
        words[gbase[b] + (p - sc[b])] = word;
    }
}

// ------------------------------------------------- fine sort: words -> words2 + rowptr
__global__ __launch_bounds__(256) void k_fsort(
    const int* __restrict__ words, int* __restrict__ words2,
    const int* __restrict__ cbase, int* __restrict__ rowptr,
    int n, int e) {
    __shared__ int rp[257];
    __shared__ int offs[256];
    __shared__ int staged[SCAP];
    __shared__ int sorted_[SCAP];
    const int b = blockIdx.x;
    const int base = cbase[b];
    const int cnt = cbase[b + 1] - base;
    const int tid = threadIdx.x;
    rp[tid] = 0;
    offs[tid] = 0;
    if (tid == 0) rp[256] = 0;
    __syncthreads();
    if (cnt <= SCAP) {
        for (int p = tid; p < cnt; p += 256) {
            int w = words[base + p];
            staged[p] = w;
            atomicAdd(&rp[(w >> 17) & 255], 1);
        }
        lds_excl_scan(rp, 256);
        for (int p = tid; p < cnt; p += 256) {
            int w = staged[p];
            int dl = (w >> 17) & 255;
            int r = atomicAdd(&offs[dl], 1);
            sorted_[rp[dl] + r] = w;
        }
        __syncthreads();
        for (int p = tid; p < cnt; p += 256) words2[base + p] = sorted_[p];
    } else {
        for (int p = tid; p < cnt; p += 256)
            atomicAdd(&rp[(words[base + p] >> 17) & 255], 1);
        lds_excl_scan(rp, 256);
        for (int p = tid; p < cnt; p += 256) {
            int w = words[base + p];
            int dl = (w >> 17) & 255;
            int r = atomicAdd(&offs[dl], 1);
            words2[base + rp[dl] + r] = w;
        }
    }
    const int d0 = b << 8;
    const int ndl = min(256, n - d0);
    if (tid < ndl) rowptr[d0 + tid] = base + rp[tid];
    if (b == (int)gridDim.x - 1 && tid == 0) rowptr[n] = e;
}

// ------------------------------------------------- softmax + aggregate
// wave per dst. deg<=64: edge segment register-resident; one gather+exp per
// edge; shfl broadcast; 8 row groups x int4(8 bf16) loads.
__global__ __launch_bounds__(256) void k_aggr(
    const unsigned short* __restrict__ h2, const float* __restrict__ a_src,
    const float* __restrict__ a_dst, const int* __restrict__ rowptr,
    const int* __restrict__ words2, float* __restrict__ out, int n) {
    const int lane = threadIdx.x & 63;
    int d = (blockIdx.x << 2) + (threadIdx.x >> 6);
    if (d >= n) return;
    d = __builtin_amdgcn_readfirstlane(d);
    const int base = rowptr[d];
    const int deg = rowptr[d + 1] - base;
    const float adst = a_dst[d];
    const float e_self = leaky(a_src[d] + adst);

    if (deg <= 64) {
        // --- fast path: lane j owns edge j ---
        int src = 0;
        float ev = -1e30f;
        if (lane < deg) {
            src = words2[base + lane] & 0x1FFFF;
            ev = leaky(a_src[src] + adst);
        }
        const float m = fmaxf(wave_max(ev), e_self);
        float w = (lane < deg) ? __expf(ev - m) : 0.f;
        float wself = __expf(e_self - m);
        const float inv = 1.0f / (wave_sum(w) + wself + 1e-16f);
        w *= inv;
        wself *= inv;

        const int r = lane >> 3;          // row group 0..7
        const int f0 = (lane & 7) << 3;   // feature octet
        float acc[8] = {0.f, 0.f, 0.f, 0.f, 0.f, 0.f, 0.f, 0.f};
        if (r == 0) {  // self loop in group 0
            int4 u = *(const int4*)(h2 + (size_t)d * 64 + f0);
            bf8_fma(acc, u, wself);
        }
        for (int c0 = 0; c0 < deg; c0 += 8) {
            int j = c0 + r;
            int sj = __shfl(src, j);
            float wj = __shfl(w, j);
            if (j < deg) {
                int4 u = *(const int4*)(h2 + (size_t)sj * 64 + f0);
                bf8_fma(acc, u, wj);
            }
        }
#pragma unroll
        for (int i = 0; i < 8; ++i) {
            acc[i] += __shfl_xor(acc[i], 8);
            acc[i] += __shfl_xor(acc[i], 16);
            acc[i] += __shfl_xor(acc[i], 32);
        }
        if (lane < 8) {
            float* op = out + (size_t)d * 64 + f0;
            *(float4*)op = make_float4(acc[0], acc[1], acc[2], acc[3]);
            *(float4*)(op + 4) = make_float4(acc[4], acc[5], acc[6], acc[7]);
        }
    } else {
        // --- fallback (deg>64, ~never for this graph): two-pass streaming ---
        float lm = -1e30f, ls = 0.f;
        for (int j = lane; j < deg; j += 64) {
            int src = words2[base + j] & 0x1FFFF;
            float ev = leaky(a_src[src] + adst);
            if (ev > lm) { ls = ls * __expf(lm - ev) + 1.f; lm = ev; }
            else ls += __expf(ev - lm);
        }
        const float m = fmaxf(wave_max(lm), e_self);
        ls *= __expf(lm - m);
        const float denom = wave_sum(ls) + __expf(e_self - m);
        const float inv = 1.0f / (denom + 1e-16f);

        const int r = lane >> 4;
        const int f0 = (lane & 15) << 2;
        float4 acc = {0.f, 0.f, 0.f, 0.f};
        if (r == 0) {
            float wgt = __expf(e_self - m) * inv;
            ushort4 u = *(const ushort4*)(h2 + (size_t)d * 64 + f0);
            acc.x = wgt * bf2f(u.x); acc.y = wgt * bf2f(u.y);
            acc.z = wgt * bf2f(u.z); acc.w = wgt * bf2f(u.w);
        }
        for (int c0 = 0; c0 < deg; c0 += 4) {
            int j = c0 + r;
            if (j < deg) {
                int src = words2[base + j] & 0x1FFFF;
                float wgt = __expf(leaky(a_src[src] + adst) - m) * inv;
                ushort4 u = *(const ushort4*)(h2 + (size_t)src * 64 + f0);
                acc.x += wgt * bf2f(u.x); acc.y += wgt * bf2f(u.y);
                acc.z += wgt * bf2f(u.z); acc.w += wgt * bf2f(u.w);
            }
        }
        acc.x += __shfl_xor(acc.x, 16); acc.y += __shfl_xor(acc.y, 16);
        acc.z += __shfl_xor(acc.z, 16); acc.w += __shfl_xor(acc.w, 16);
        acc.x += __shfl_xor(acc.x, 32); acc.y += __shfl_xor(acc.y, 32);
        acc.z += __shfl_xor(acc.z, 32); acc.w += __shfl_xor(acc.w, 32);
        if (lane < 16) *(float4*)(out + (size_t)d * 64 + f0) = acc;
    }
}

extern "C" void kernel_launch(void* const* d_in, const int* in_sizes, int n_in,
                              void* d_out, int out_size, void* d_ws, size_t ws_size,
                              hipStream_t stream) {
    const float* x = (const float*)d_in[0];
    const float* W = (const float*)d_in[1];
    const float* att_s = (const float*)d_in[2];
    const float* att_d = (const float*)d_in[3];
    const int* ei = (const int*)d_in[4];
    const int n = in_sizes[0] / 128;
    const int e = in_sizes[4] / 2;
    const int* srcv = ei;
    const int* dstv = ei + e;
    float* out = (float*)d_out;

    char* ws = (char*)d_ws;
    size_t off = 0;
    auto carve = [&](size_t bytes) -> void* {
        void* p = ws + off;
        off = (off + bytes + 63) & ~(size_t)63;
        return p;
    };
    unsigned short* h2 = (unsigned short*)carve((size_t)n * 64 * 2);
    float* a_src  = (float*)carve((size_t)n * 4);
    float* a_dst  = (float*)carve((size_t)n * 4);
    int* chist    = (int*)carve((size_t)(NBC_MAX + 1) * 4);
    int* gcursor  = (int*)carve((size_t)NBC_MAX * 4);
    int* cbase    = (int*)carve((size_t)(NBC_MAX + 1) * 4);
    int* rowptr   = (int*)carve((size_t)(n + 1) * 4);
    int* words    = (int*)carve((size_t)e * 4);
    int* words2   = (int*)carve((size_t)e * 4);
    (void)ws_size; (void)n_in; (void)out_size;

    const int nbc = (n + 255) >> 8;
    const int neb = (e + 4095) / 4096;

    size_t zspan = (size_t)((char*)(gcursor + NBC_MAX) - (char*)chist);
    hipMemsetAsync(chist, 0, zspan, stream);

    k_gemm<<<(n + 31) / 32, 256, 0, stream>>>(x, W, att_s, att_d, h2, a_src, a_dst, n);
    k_chist<<<neb, 256, 0, stream>>>(dstv, chist, e, nbc);
    k_cscan<<<1, 256, 0, stream>>>(chist, cbase, gcursor, nbc);
    k_cscatter<<<neb, 256, 0, stream>>>(srcv, dstv, gcursor, words, e, nbc);
    k_fsort<<<nbc, 256, 0, stream>>>(words, words2, cbase, rowptr, n, e);
    k_aggr<<<(n + 3) / 4, 256, 0, stream>>>(h2, a_src, a_dst, rowptr, words2, out, n);
}

// Round 8
// 134.479 us; speedup vs baseline: 2.3636x; 1.2503x over previous
//
#include <hip/hip_runtime.h>

// GATConv fused pipeline, MI355X.
// R8: k_gemm -> MFMA (3-term split-bf16: xh*Wh + xl*Wh + xh*Wl ~= fp32).
// R7 counters: k_gemm 64us, LDS-throughput-bound scalar-FMA loop (12 LDS
// reads / 32 FMAs per iter). x frags now load direct from global (rows have
// zero reuse); W staged once as bf16 hi/lo transposed [col][136] in LDS.
// A-frag: row=lane&15, k=(lane>>4)*8+j. B-frag: col=lane&15, same k.
// C/D: col=lane&15, row=(lane>>4)*4+reg (m89-verified layout).
// Sort pipeline + aggr unchanged from R7. word = dst_low:8 | src:17.

#define NEG_SLOPE 0.2f
#define NBC_MAX 512
#define SCAP 6144

typedef __attribute__((ext_vector_type(8))) short bf16x8;
typedef __attribute__((ext_vector_type(4))) float f32x4;

__device__ __forceinline__ float leaky(float v) {
    return v > 0.f ? v : NEG_SLOPE * v;
}
__device__ __forceinline__ float wave_sum(float v) {
    for (int o = 32; o; o >>= 1) v += __shfl_xor(v, o);
    return v;
}
__device__ __forceinline__ float wave_max(float v) {
    for (int o = 32; o; o >>= 1) v = fmaxf(v, __shfl_xor(v, o));
    return v;
}
__device__ __forceinline__ unsigned short f2bf(float f) {
    unsigned b = __float_as_uint(f);
    return (unsigned short)((b + 0x7FFFu + ((b >> 16) & 1u)) >> 16);
}
__device__ __forceinline__ float bf2f(unsigned short u) {
    return __uint_as_float(((unsigned)u) << 16);
}
// fma 8 bf16 features (packed in int4) into acc[8] with weight w
__device__ __forceinline__ void bf8_fma(float* acc, int4 u, float w) {
    acc[0] = fmaf(__uint_as_float((unsigned)u.x << 16), w, acc[0]);
    acc[1] = fmaf(__uint_as_float((unsigned)u.x & 0xFFFF0000u), w, acc[1]);
    acc[2] = fmaf(__uint_as_float((unsigned)u.y << 16), w, acc[2]);
    acc[3] = fmaf(__uint_as_float((unsigned)u.y & 0xFFFF0000u), w, acc[3]);
    acc[4] = fmaf(__uint_as_float((unsigned)u.z << 16), w, acc[4]);
    acc[5] = fmaf(__uint_as_float((unsigned)u.z & 0xFFFF0000u), w, acc[5]);
    acc[6] = fmaf(__uint_as_float((unsigned)u.w << 16), w, acc[6]);
    acc[7] = fmaf(__uint_as_float((unsigned)u.w & 0xFFFF0000u), w, acc[7]);
}

// exclusive scan of sd[0..len) in place; sd must have len+1 slots.
__device__ __forceinline__ void lds_excl_scan(int* sd, int len) {
    __syncthreads();
    if (threadIdx.x < 64) {
        int lane = threadIdx.x;
        int carry = 0;
        for (int c0 = 0; c0 < len; c0 += 64) {
            int idx = c0 + lane;
            int v = (idx < len) ? sd[idx] : 0;
            int s = v;
            for (int off = 1; off < 64; off <<= 1) {
                int t = __shfl_up(s, off);
                if (lane >= off) s += t;
            }
            if (idx < len) sd[idx] = carry + s - v;
            carry += __shfl(s, 63);
        }
        if (lane == 0) sd[len] = carry;
    }
    __syncthreads();
}

// ------------------------------------------------- h(bf16) = x@W via MFMA
// block: 4 waves x 16 rows. W -> LDS bf16 hi/lo transposed [col][136] (pad 8).
__global__ __launch_bounds__(256) void k_gemm(
    const float* __restrict__ x, const float* __restrict__ Wg,
    const float* __restrict__ att_s, const float* __restrict__ att_d,
    unsigned short* __restrict__ h2, float* __restrict__ a_src,
    float* __restrict__ a_dst, int n) {
    __shared__ unsigned short Wh[64 * 136];   // 17 KB
    __shared__ unsigned short Wl2[64 * 136];  // 17 KB
    {
        const float4* wg4 = (const float4*)Wg;  // [k=128][col=64] row-major
#pragma unroll
        for (int i = 0; i < 8; ++i) {
            int f = threadIdx.x + i * 256;  // [0, 2048)
            float4 w = wg4[f];
            int k = f >> 4;
            int c0 = (f & 15) << 2;
            float vv[4] = {w.x, w.y, w.z, w.w};
#pragma unroll
            for (int j = 0; j < 4; ++j) {
                unsigned short hi = f2bf(vv[j]);
                Wh[(c0 + j) * 136 + k] = hi;
                Wl2[(c0 + j) * 136 + k] = f2bf(vv[j] - bf2f(hi));
            }
        }
    }
    __syncthreads();

    const int lane = threadIdx.x & 63;
    const int wave = threadIdx.x >> 6;
    const int rb = blockIdx.x * 64 + wave * 16;  // wave's 16-row tile
    const int arow = rb + (lane & 15);           // A-frag row for this lane
    const int kb = (lane >> 4) << 3;             // k sub-offset 0/8/16/24
    const int col = lane & 15;

    f32x4 acc[4];
#pragma unroll
    for (int ct = 0; ct < 4; ++ct) acc[ct] = (f32x4){0.f, 0.f, 0.f, 0.f};

#pragma unroll
    for (int ks = 0; ks < 4; ++ks) {
        const int k0 = ks * 32 + kb;
        float av[8];
        if (arow < n) {
            float4 a0 = *(const float4*)(x + (size_t)arow * 128 + k0);
            float4 a1 = *(const float4*)(x + (size_t)arow * 128 + k0 + 4);
            av[0] = a0.x; av[1] = a0.y; av[2] = a0.z; av[3] = a0.w;
            av[4] = a1.x; av[5] = a1.y; av[6] = a1.z; av[7] = a1.w;
        } else {
#pragma unroll
            for (int j = 0; j < 8; ++j) av[j] = 0.f;
        }
        bf16x8 ah, al;
#pragma unroll
        for (int j = 0; j < 8; ++j) {
            unsigned short hi = f2bf(av[j]);
            ah[j] = (short)hi;
            al[j] = (short)f2bf(av[j] - bf2f(hi));
        }
#pragma unroll
        for (int ct = 0; ct < 4; ++ct) {
            const bf16x8 bh = *(const bf16x8*)(&Wh[(ct * 16 + col) * 136 + k0]);
            const bf16x8 bl = *(const bf16x8*)(&Wl2[(ct * 16 + col) * 136 + k0]);
            acc[ct] = __builtin_amdgcn_mfma_f32_16x16x32_bf16(ah, bh, acc[ct], 0, 0, 0);
            acc[ct] = __builtin_amdgcn_mfma_f32_16x16x32_bf16(al, bh, acc[ct], 0, 0, 0);
            acc[ct] = __builtin_amdgcn_mfma_f32_16x16x32_bf16(ah, bl, acc[ct], 0, 0, 0);
        }
    }

    // epilogue: C/D layout col=lane&15, row=(lane>>4)*4+reg
    float as_f[4], ad_f[4];
#pragma unroll
    for (int ct = 0; ct < 4; ++ct) {
        as_f[ct] = att_s[ct * 16 + col];
        ad_f[ct] = att_d[ct * 16 + col];
    }
#pragma unroll
    for (int reg = 0; reg < 4; ++reg) {
        const int row = rb + ((lane >> 4) << 2) + reg;
        float s = 0.f, t = 0.f;
#pragma unroll
        for (int ct = 0; ct < 4; ++ct) {
            float v = acc[ct][reg];
            s = fmaf(v, as_f[ct], s);
            t = fmaf(v, ad_f[ct], t);
            if (row < n) h2[(size_t)row * 64 + ct * 16 + col] = f2bf(v);
        }
#pragma unroll
        for (int o = 1; o < 16; o <<= 1) {
            s += __shfl_xor(s, o);
            t += __shfl_xor(t, o);
        }
        if (col == 0 && row < n) { a_src[row] = s; a_dst[row] = t; }
    }
}

// ------------------------------------------------- coarse histogram
__global__ __launch_bounds__(256) void k_chist(const int* __restrict__ dstv,
                                               int* __restrict__ chist,
                                               int e, int nbc) {
    __shared__ int hl[NBC_MAX];
    for (int t = threadIdx.x; t < nbc; t += 256) hl[t] = 0;
    __syncthreads();
    const int base = blockIdx.x * 4096;
    for (int k = 0; k < 16; ++k) {
        int i = base + k * 256 + threadIdx.x;
        if (i < e) atomicAdd(&hl[dstv[i] >> 8], 1);
    }
    __syncthreads();
    for (int t = threadIdx.x; t < nbc; t += 256) {
        int c = hl[t];
        if (c) atomicAdd(&chist[t], c);
    }
}

// ------------------------------------------------- coarse scan (1 block)
__global__ __launch_bounds__(256) void k_cscan(const int* __restrict__ chist,
                                               int* __restrict__ cbase,
                                               int* __restrict__ gcursor, int nbc) {
    __shared__ int sc[NBC_MAX + 1];
    for (int t = threadIdx.x; t < nbc; t += 256) sc[t] = chist[t];
    lds_excl_scan(sc, nbc);
    for (int t = threadIdx.x; t <= nbc; t += 256) {
        cbase[t] = sc[t];
        if (t < nbc) gcursor[t] = sc[t];
    }
}

// ------------------------------------------------- coarse scatter (LDS reorder)
__global__ __launch_bounds__(256) void k_cscatter(
    const int* __restrict__ srcv, const int* __restrict__ dstv,
    int* __restrict__ gcursor, int* __restrict__ words, int e, int nbc) {
    __shared__ int sc[NBC_MAX + 1];
    __shared__ int offs[NBC_MAX];
    __shared__ int gbase[NBC_MAX];
    __shared__ int2 staged[4096];
    for (int t = threadIdx.x; t < nbc; t += 256) { sc[t] = 0; offs[t] = 0; }
    __syncthreads();
    const int base = blockIdx.x * 4096;
    int s_[16], d_[16];
#pragma unroll
    for (int k = 0; k < 16; ++k) {
        int i = base + k * 256 + threadIdx.x;
        if (i < e) {
            s_[k] = srcv[i];
            d_[k] = dstv[i];
            atomicAdd(&sc[d_[k] >> 8], 1);
        } else {
            d_[k] = -1;
        }
    }
    lds_excl_scan(sc, nbc);
    for (int t = threadIdx.x; t < nbc; t += 256) {
        int c = sc[t + 1] - sc[t];
        if (c) gbase[t] = atomicAdd(&gcursor[t], c);
    }
    __syncthreads();
#pragma unroll
    for (int k = 0; k < 16; ++k) {
        if (d_[k] >= 0) {
            int b = d_[k] >> 8;
            int r = atomicAdd(&offs[b], 1);
            staged[sc[b] + r] = make_int2(s_[k], d_[k]);
        }
    }
    __syncthreads();
    const int tot = sc[nbc];
    for (int p = threadIdx.x; p < tot; p += 256) {
        int2 pr = staged[p];
        int b = pr.y >> 8;
        int word = ((pr.y & 255) << 17) | pr.x;  // dst_low:8 | src:17
        words[gbase[b] + (p - sc[b])] = word;
    }
}

// ------------------------------------------------- fine sort: words -> words2 + rowptr
__global__ __launch_bounds__(256) void k_fsort(
    const int* __restrict__ words, int* __restrict__ words2,
    const int* __restrict__ cbase, int* __restrict__ rowptr,
    int n, int e) {
    __shared__ int rp[257];
    __shared__ int offs[256];
    __shared__ int staged[SCAP];
    __shared__ int sorted_[SCAP];
    const int b = blockIdx.x;
    const int base = cbase[b];
    const int cnt = cbase[b + 1] - base;
    const int tid = threadIdx.x;
    rp[tid] = 0;
    offs[tid] = 0;
    if (tid == 0) rp[256] = 0;
    __syncthreads();
    if (cnt <= SCAP) {
        for (int p = tid; p < cnt; p += 256) {
            int w = words[base + p];
            staged[p] = w;
            atomicAdd(&rp[(w >> 17) & 255], 1);
        }
        lds_excl_scan(rp, 256);
        for (int p = tid; p < cnt; p += 256) {
            int w = staged[p];
            int dl = (w >> 17) & 255;
            int r = atomicAdd(&offs[dl], 1);
            sorted_[rp[dl] + r] = w;
        }
        __syncthreads();
        for (int p = tid; p < cnt; p += 256) words2[base + p] = sorted_[p];
    } else {
        for (int p = tid; p < cnt; p += 256)
            atomicAdd(&rp[(words[base + p] >> 17) & 255], 1);
        lds_excl_scan(rp, 256);
        for (int p = tid; p < cnt; p += 256) {
            int w = words[base + p];
            int dl = (w >> 17) & 255;
            int r = atomicAdd(&offs[dl], 1);
            words2[base + rp[dl] + r] = w;
        }
    }
    const int d0 = b << 8;
    const int ndl = min(256, n - d0);
    if (tid < ndl) rowptr[d0 + tid] = base + rp[tid];
    if (b == (int)gridDim.x - 1 && tid == 0) rowptr[n] = e;
}

// ------------------------------------------------- softmax + aggregate
__global__ __launch_bounds__(256) void k_aggr(
    const unsigned short* __restrict__ h2, const float* __restrict__ a_src,
    const float* __restrict__ a_dst, const int* __restrict__ rowptr,
    const int* __restrict__ words2, float* __restrict__ out, int n) {
    const int lane = threadIdx.x & 63;
    int d = (blockIdx.x << 2) + (threadIdx.x >> 6);
    if (d >= n) return;
    d = __builtin_amdgcn_readfirstlane(d);
    const int base = rowptr[d];
    const int deg = rowptr[d + 1] - base;
    const float adst = a_dst[d];
    const float e_self = leaky(a_src[d] + adst);

    if (deg <= 64) {
        int src = 0;
        float ev = -1e30f;
        if (lane < deg) {
            src = words2[base + lane] & 0x1FFFF;
            ev = leaky(a_src[src] + adst);
        }
        const float m = fmaxf(wave_max(ev), e_self);
        float w = (lane < deg) ? __expf(ev - m) : 0.f;
        float wself = __expf(e_self - m);
        const float inv = 1.0f / (wave_sum(w) + wself + 1e-16f);
        w *= inv;
        wself *= inv;

        const int r = lane >> 3;
        const int f0 = (lane & 7) << 3;
        float acc[8] = {0.f, 0.f, 0.f, 0.f, 0.f, 0.f, 0.f, 0.f};
        if (r == 0) {
            int4 u = *(const int4*)(h2 + (size_t)d * 64 + f0);
            bf8_fma(acc, u, wself);
        }
        for (int c0 = 0; c0 < deg; c0 += 8) {
            int j = c0 + r;
            int sj = __shfl(src, j);
            float wj = __shfl(w, j);
            if (j < deg) {
                int4 u = *(const int4*)(h2 + (size_t)sj * 64 + f0);
                bf8_fma(acc, u, wj);
            }
        }
#pragma unroll
        for (int i = 0; i < 8; ++i) {
            acc[i] += __shfl_xor(acc[i], 8);
            acc[i] += __shfl_xor(acc[i], 16);
            acc[i] += __shfl_xor(acc[i], 32);
        }
        if (lane < 8) {
            float* op = out + (size_t)d * 64 + f0;
            *(float4*)op = make_float4(acc[0], acc[1], acc[2], acc[3]);
            *(float4*)(op + 4) = make_float4(acc[4], acc[5], acc[6], acc[7]);
        }
    } else {
        float lm = -1e30f, ls = 0.f;
        for (int j = lane; j < deg; j += 64) {
            int src = words2[base + j] & 0x1FFFF;
            float ev = leaky(a_src[src] + adst);
            if (ev > lm) { ls = ls * __expf(lm - ev) + 1.f; lm = ev; }
            else ls += __expf(ev - lm);
        }
        const float m = fmaxf(wave_max(lm), e_self);
        ls *= __expf(lm - m);
        const float denom = wave_sum(ls) + __expf(e_self - m);
        const float inv = 1.0f / (denom + 1e-16f);

        const int r = lane >> 4;
        const int f0 = (lane & 15) << 2;
        float4 acc = {0.f, 0.f, 0.f, 0.f};
        if (r == 0) {
            float wgt = __expf(e_self - m) * inv;
            ushort4 u = *(const ushort4*)(h2 + (size_t)d * 64 + f0);
            acc.x = wgt * bf2f(u.x); acc.y = wgt * bf2f(u.y);
            acc.z = wgt * bf2f(u.z); acc.w = wgt * bf2f(u.w);
        }
        for (int c0 = 0; c0 < deg; c0 += 4) {
            int j = c0 + r;
            if (j < deg) {
                int src = words2[base + j] & 0x1FFFF;
                float wgt = __expf(leaky(a_src[src] + adst) - m) * inv;
                ushort4 u = *(const ushort4*)(h2 + (size_t)src * 64 + f0);
                acc.x += wgt * bf2f(u.x); acc.y += wgt * bf2f(u.y);
                acc.z += wgt * bf2f(u.z); acc.w += wgt * bf2f(u.w);
            }
        }
        acc.x += __shfl_xor(acc.x, 16); acc.y += __shfl_xor(acc.y, 16);
        acc.z += __shfl_xor(acc.z, 16); acc.w += __shfl_xor(acc.w, 16);
        acc.x += __shfl_xor(acc.x, 32); acc.y += __shfl_xor(acc.y, 32);
        acc.z += __shfl_xor(acc.z, 32); acc.w += __shfl_xor(acc.w, 32);
        if (lane < 16) *(float4*)(out + (size_t)d * 64 + f0) = acc;
    }
}

extern "C" void kernel_launch(void* const* d_in, const int* in_sizes, int n_in,
                              void* d_out, int out_size, void* d_ws, size_t ws_size,
                              hipStream_t stream) {
    const float* x = (const float*)d_in[0];
    const float* W = (const float*)d_in[1];
    const float* att_s = (const float*)d_in[2];
    const float* att_d = (const float*)d_in[3];
    const int* ei = (const int*)d_in[4];
    const int n = in_sizes[0] / 128;
    const int e = in_sizes[4] / 2;
    const int* srcv = ei;
    const int* dstv = ei + e;
    float* out = (float*)d_out;

    char* ws = (char*)d_ws;
    size_t off = 0;
    auto carve = [&](size_t bytes) -> void* {
        void* p = ws + off;
        off = (off + bytes + 63) & ~(size_t)63;
        return p;
    };
    unsigned short* h2 = (unsigned short*)carve((size_t)n * 64 * 2);
    float* a_src  = (float*)carve((size_t)n * 4);
    float* a_dst  = (float*)carve((size_t)n * 4);
    int* chist    = (int*)carve((size_t)(NBC_MAX + 1) * 4);
    int* gcursor  = (int*)carve((size_t)NBC_MAX * 4);
    int* cbase    = (int*)carve((size_t)(NBC_MAX + 1) * 4);
    int* rowptr   = (int*)carve((size_t)(n + 1) * 4);
    int* words    = (int*)carve((size_t)e * 4);
    int* words2   = (int*)carve((size_t)e * 4);
    (void)ws_size; (void)n_in; (void)out_size;

    const int nbc = (n + 255) >> 8;
    const int neb = (e + 4095) / 4096;

    size_t zspan = (size_t)((char*)(gcursor + NBC_MAX) - (char*)chist);
    hipMemsetAsync(chist, 0, zspan, stream);

    k_gemm<<<(n + 63) / 64, 256, 0, stream>>>(x, W, att_s, att_d, h2, a_src, a_dst, n);
    k_chist<<<neb, 256, 0, stream>>>(dstv, chist, e, nbc);
    k_cscan<<<1, 256, 0, stream>>>(chist, cbase, gcursor, nbc);
    k_cscatter<<<neb, 256, 0, stream>>>(srcv, dstv, gcursor, words, e, nbc);
    k_fsort<<<nbc, 256, 0, stream>>>(words, words2, cbase, rowptr, n, e);
    k_aggr<<<(n + 3) / 4, 256, 0, stream>>>(h2, a_src, a_dst, rowptr, words2, out, n);
}